// Round 1
// baseline (204.310 us; speedup 1.0000x reference)
//
#include <hip/hip_runtime.h>
#include <hip/hip_bf16.h>
#include <stdint.h>

#define NH   8
#define DIM  512
#define NP   1024
#define MNP  4096
#define BS   4
#define TOPK 32
#define DH   64

typedef __attribute__((ext_vector_type(8))) short bf16x8;
typedef __attribute__((ext_vector_type(4))) float f32x4;

__device__ __forceinline__ unsigned short f2bf(float f) {
    union { float f; unsigned u; } x; x.f = f;
    unsigned r = x.u + 0x7FFFu + ((x.u >> 16) & 1u);   // RNE
    return (unsigned short)(r >> 16);
}
__device__ __forceinline__ float bf2f(unsigned short h) {
    union { unsigned u; float f; } x; x.u = ((unsigned)h) << 16;
    return x.f;
}

// ---------------- fp32 -> bf16 conversion (weights) ----------------
__global__ void cvt_f32_bf16(const float* __restrict__ src,
                             unsigned short* __restrict__ dst, int n) {
    int i = (blockIdx.x * blockDim.x + threadIdx.x) * 4;
    if (i + 3 < n) {
        float4 v = *(const float4*)(src + i);
        ushort4 o;
        o.x = f2bf(v.x); o.y = f2bf(v.y); o.z = f2bf(v.z); o.w = f2bf(v.w);
        *(ushort4*)(dst + i) = o;
    } else {
        for (int j = i; j < n; j++) dst[j] = f2bf(src[j]);
    }
}

// ---------------- projection GEMM: C[m][e] = sum_d A[m][d]*W[e][d] + bias[e]
// A fp32 row-major (M x 512), W bf16 (512 x 512) row-major over d, C bf16.
#define BM 128
#define BN 128
#define BK 64
#define LDT 72   // padded LDS row stride (bf16 elems): 2-way bank alias only

__global__ __launch_bounds__(256, 2)
void proj_gemm(const float* __restrict__ A, const unsigned short* __restrict__ W,
               const float* __restrict__ bias, unsigned short* __restrict__ C) {
    __shared__ unsigned short As[BM * LDT];
    __shared__ unsigned short Bs[BN * LDT];

    const int tid  = threadIdx.x;
    const int bm   = blockIdx.y * BM;
    const int bn   = blockIdx.x * BN;
    const int wave = tid >> 6;
    const int lane = tid & 63;
    const int wm   = (wave & 1) * 64;
    const int wn   = (wave >> 1) * 64;
    const int l16  = lane & 15;
    const int quad = lane >> 4;

    f32x4 acc[4][4] = {};

    // staging assignments
    const int a_c4 = (tid & 15) * 4;   // float col 0..60
    const int a_r0 = tid >> 4;         // 0..15, 8 rows stride 16
    const int b_c8 = (tid & 7) * 8;    // ushort col 0..56
    const int b_r0 = tid >> 3;         // 0..31, 4 rows stride 32

    for (int k0 = 0; k0 < 512; k0 += BK) {
        __syncthreads();
#pragma unroll
        for (int rr = 0; rr < 8; rr++) {
            int row = a_r0 + rr * 16;
            float4 v = *(const float4*)(A + (size_t)(bm + row) * 512 + k0 + a_c4);
            ushort4 o;
            o.x = f2bf(v.x); o.y = f2bf(v.y); o.z = f2bf(v.z); o.w = f2bf(v.w);
            *(ushort4*)(&As[row * LDT + a_c4]) = o;
        }
#pragma unroll
        for (int rr = 0; rr < 4; rr++) {
            int row = b_r0 + rr * 32;
            uint4 p = *(const uint4*)(W + (size_t)(bn + row) * 512 + k0 + b_c8);
            *(uint4*)(&Bs[row * LDT + b_c8]) = p;
        }
        __syncthreads();
#pragma unroll
        for (int kk = 0; kk < BK; kk += 32) {
            bf16x8 af[4], bfr[4];
#pragma unroll
            for (int i = 0; i < 4; i++) {
                af[i]  = *(const bf16x8*)(&As[(wm + i * 16 + l16) * LDT + kk + quad * 8]);
                bfr[i] = *(const bf16x8*)(&Bs[(wn + i * 16 + l16) * LDT + kk + quad * 8]);
            }
#pragma unroll
            for (int i = 0; i < 4; i++)
#pragma unroll
                for (int j = 0; j < 4; j++)
                    acc[i][j] = __builtin_amdgcn_mfma_f32_16x16x32_bf16(
                        af[i], bfr[j], acc[i][j], 0, 0, 0);
        }
    }
    // epilogue: C/D layout col=lane&15, row=quad*4+reg
#pragma unroll
    for (int i = 0; i < 4; i++) {
        int row = bm + wm + i * 16 + quad * 4;
#pragma unroll
        for (int j = 0; j < 4; j++) {
            int col = bn + wn + j * 16 + l16;
            float bv = bias[col];
#pragma unroll
            for (int r = 0; r < 4; r++)
                C[(size_t)(row + r) * 512 + col] = f2bf(acc[i][j][r] + bv);
        }
    }
}

// ---------------- top-k gather attention ----------------
// one block per (n,b): dedupe 32 indices, scores (32 idx x 8 heads),
// per-head softmax, weighted V gather.
__global__ __launch_bounds__(256)
void attn_kernel(const unsigned short* __restrict__ Qh,
                 const unsigned short* __restrict__ Kh,
                 const unsigned short* __restrict__ Vh,
                 const int* __restrict__ rns,
                 float* __restrict__ out) {
    __shared__ float sq[NH * 72];      // padded: bank-conflict-free per-head reads
    __shared__ int   sidx[TOPK];
    __shared__ int   srow[TOPK];
    __shared__ float sval[TOPK];
    __shared__ float ss[TOPK][NH];
    __shared__ float sw[TOPK][NH];

    const int bid = blockIdx.x;
    const int n = bid >> 2;
    const int b = bid & 3;
    const int tid = threadIdx.x;

    if (tid < TOPK) {
        int mi = rns[((b * NP + n) * TOPK) + tid];
        sidx[tid] = mi;
        srow[tid] = (mi * BS + b) * DIM;
    }
    {   // q row -> LDS fp32, padded layout sq[h][72]
        const unsigned short* qrow = Qh + (size_t)(n * BS + b) * DIM;
        unsigned int u = *(const unsigned int*)(qrow + tid * 2);
        int e0 = tid * 2;
        sq[(e0 >> 6) * 72 + (e0 & 63)]     = bf2f((unsigned short)(u & 0xffff));
        sq[(e0 >> 6) * 72 + ((e0 + 1) & 63)] = bf2f((unsigned short)(u >> 16));
    }
    __syncthreads();
    if (tid < TOPK) {   // dedupe: keep first occurrence
        float v = 1.0f;
        int me = sidx[tid];
        for (int j = 0; j < tid; j++)
            if (sidx[j] == me) v = 0.0f;
        sval[tid] = v;
    }
    __syncthreads();
    {   // scores: thread t -> (idx slot i, head h)
        const int i = tid >> 3;
        const int h = tid & 7;
        const unsigned short* krow = Kh + srow[i] + h * DH;
        const float* qh = sq + h * 72;
        float acc = 0.f;
#pragma unroll
        for (int d = 0; d < DH; d += 8) {
            uint4 kv = *(const uint4*)(krow + d);
            acc += qh[d + 0] * bf2f((unsigned short)(kv.x & 0xffff))
                 + qh[d + 1] * bf2f((unsigned short)(kv.x >> 16))
                 + qh[d + 2] * bf2f((unsigned short)(kv.y & 0xffff))
                 + qh[d + 3] * bf2f((unsigned short)(kv.y >> 16))
                 + qh[d + 4] * bf2f((unsigned short)(kv.z & 0xffff))
                 + qh[d + 5] * bf2f((unsigned short)(kv.z >> 16))
                 + qh[d + 6] * bf2f((unsigned short)(kv.w & 0xffff))
                 + qh[d + 7] * bf2f((unsigned short)(kv.w >> 16));
        }
        ss[i][h] = (sval[i] > 0.f) ? acc * 0.125f : -1e30f;
    }
    __syncthreads();
    if (tid < NH) {   // per-head softmax (dup slots -> exp(-1e30-m)=0, matches ref)
        const int h = tid;
        float m = -1e30f;
        for (int i = 0; i < TOPK; i++) m = fmaxf(m, ss[i][h]);
        float s = 0.f;
        for (int i = 0; i < TOPK; i++) {
            float e = __expf(ss[i][h] - m);
            sw[i][h] = e; s += e;
        }
        float inv = 1.0f / s;
        for (int i = 0; i < TOPK; i++) sw[i][h] *= inv;
    }
    __syncthreads();
    {   // out[n,b,e] = sum_i w[i][e/64] * Vh[row_i][e], 2 elems/thread
        const int e0 = tid * 2;
        const int h = e0 >> 6;
        float a0 = 0.f, a1 = 0.f;
#pragma unroll 8
        for (int i = 0; i < TOPK; i++) {
            float w = sw[i][h];
            unsigned int vv = *(const unsigned int*)(Vh + srow[i] + e0);
            a0 += w * bf2f((unsigned short)(vv & 0xffff));
            a1 += w * bf2f((unsigned short)(vv >> 16));
        }
        float2* o = (float2*)(out + (size_t)(n * BS + b) * DIM + e0);
        *o = make_float2(a0, a1);
    }
}

extern "C" void kernel_launch(void* const* d_in, const int* in_sizes, int n_in,
                              void* d_out, int out_size, void* d_ws, size_t ws_size,
                              hipStream_t stream) {
    const float* q  = (const float*)d_in[0];
    const float* k  = (const float*)d_in[1];
    const float* v  = (const float*)d_in[2];
    const int* rns  = (const int*)d_in[3];
    const float* W1 = (const float*)d_in[4];
    const float* b1 = (const float*)d_in[5];
    const float* W2 = (const float*)d_in[6];
    const float* b2 = (const float*)d_in[7];
    const float* W3 = (const float*)d_in[8];
    const float* b3 = (const float*)d_in[9];
    float* out = (float*)d_out;

    unsigned short* ws  = (unsigned short*)d_ws;
    unsigned short* Wb1 = ws;                  // 512*512
    unsigned short* Wb2 = Wb1 + 262144;
    unsigned short* Wb3 = Wb2 + 262144;
    unsigned short* Qh  = Wb3 + 262144;        // 4096*512
    unsigned short* Kh  = Qh  + 2097152;       // 16384*512
    unsigned short* Vh  = Kh  + 8388608;       // 16384*512
    // total ws use: 19,660,800 ushorts = 37.5 MB

    cvt_f32_bf16<<<256, 256, 0, stream>>>(W1, Wb1, 262144);
    cvt_f32_bf16<<<256, 256, 0, stream>>>(W2, Wb2, 262144);
    cvt_f32_bf16<<<256, 256, 0, stream>>>(W3, Wb3, 262144);

    dim3 blk(256);
    proj_gemm<<<dim3(4, 32),  blk, 0, stream>>>(q, Wb1, b1, Qh);   // M=4096
    proj_gemm<<<dim3(4, 128), blk, 0, stream>>>(k, Wb2, b2, Kh);   // M=16384
    proj_gemm<<<dim3(4, 128), blk, 0, stream>>>(v, Wb3, b3, Vh);   // M=16384

    attn_kernel<<<NP * BS, 256, 0, stream>>>(Qh, Kh, Vh, rns, out);
}

// Round 2
// 198.667 us; speedup vs baseline: 1.0284x; 1.0284x over previous
//
#include <hip/hip_runtime.h>
#include <stdint.h>

#define NH   8
#define DIM  512
#define NP   1024
#define MNP  4096
#define BS   4
#define TOPK 32
#define DH   64

typedef unsigned short u16;
typedef __attribute__((ext_vector_type(8))) short bf16x8;
typedef __attribute__((ext_vector_type(4))) float f32x4;

__device__ __forceinline__ u16 f2bf(float f) {
    union { float f; unsigned u; } x; x.f = f;
    unsigned r = x.u + 0x7FFFu + ((x.u >> 16) & 1u);   // RNE
    return (u16)(r >> 16);
}
__device__ __forceinline__ float bf2f(u16 h) {
    union { unsigned u; float f; } x; x.u = ((unsigned)h) << 16;
    return x.f;
}

// async 16B global -> LDS (global_load_lds_dwordx4). LDS dest must be
// wave-uniform base + lane*16 (contiguous in lane order, no padding).
__device__ __forceinline__ void async16(const void* g, void* l) {
    __builtin_amdgcn_global_load_lds(
        (const __attribute__((address_space(1))) unsigned int*)g,
        (__attribute__((address_space(3))) unsigned int*)l, 16, 0, 0);
}

// ---------------- single fp32 -> bf16 pass: W1|W2|W3 -> wall, q|k|v -> act
// segment boundaries are multiples of 262144 elems -> no straddle at x4 granularity
__global__ void cvt_all(const float* __restrict__ W1, const float* __restrict__ W2,
                        const float* __restrict__ W3, const float* __restrict__ q,
                        const float* __restrict__ k,  const float* __restrict__ v,
                        u16* __restrict__ wall, u16* __restrict__ act) {
    size_t i = ((size_t)blockIdx.x * 256 + threadIdx.x) * 4;
    const float* s; u16* d;
    if (i < 786432) {
        d = wall + i;
        s = (i < 262144) ? W1 + i : (i < 524288) ? W2 + (i - 262144) : W3 + (i - 524288);
    } else {
        size_t j = i - 786432;
        d = act + j;
        s = (j < 2097152) ? q + j : (j < 10485760) ? k + (j - 2097152) : v + (j - 10485760);
    }
    float4 val = *(const float4*)s;
    ushort4 o;
    o.x = f2bf(val.x); o.y = f2bf(val.y); o.z = f2bf(val.z); o.w = f2bf(val.w);
    *(ushort4*)d = o;
}

// ---------------- fused projection GEMM (z selects q/k/v)
// C[m][e] = sum_d A[m][d]*W[e][d] + bias[e]; all bf16 in, bf16 out.
// m97-style: global_load_lds width=16, unpadded 128B LDS rows, 128x128xBK64.
__global__ __launch_bounds__(256, 2)
void proj_gemm(const u16* __restrict__ act, const u16* __restrict__ wall,
               const float* __restrict__ b1, const float* __restrict__ b2,
               const float* __restrict__ b3, u16* __restrict__ outall) {
    __shared__ u16 As[128 * 64];
    __shared__ u16 Bs[128 * 64];

    const int z = blockIdx.z;
    if (z == 0 && blockIdx.y >= 32) return;   // q has M=4096 (32 y-tiles)
    const size_t aoff = (z == 0) ? 0u : (z == 1) ? 2097152u : 10485760u;
    const u16* A = act + aoff;
    const u16* W = wall + (size_t)z * 262144;
    const float* bias = (z == 0) ? b1 : (z == 1) ? b2 : b3;
    u16* C = outall + aoff;

    const int tid  = threadIdx.x;
    const int bm   = blockIdx.y * 128;
    const int bn   = blockIdx.x * 128;
    const int wave = tid >> 6;
    const int lane = tid & 63;
    const int wm   = (wave & 1) * 64;
    const int wn   = (wave >> 1) * 64;
    const int l16  = lane & 15;
    const int quad = lane >> 4;

    const int srow = lane >> 3;        // 0..7
    const int scol = (lane & 7) * 8;   // 0..56 (bf16 elems, 16B granules)

    f32x4 acc[4][4] = {};

    for (int k0 = 0; k0 < 512; k0 += 64) {
        __syncthreads();
#pragma unroll
        for (int r = 0; r < 4; r++) {
            int row = wave * 32 + r * 8;        // wave-uniform LDS base row
            async16(A + (size_t)(bm + row + srow) * 512 + k0 + scol,
                    &As[row * 64 + lane * 8]);
            async16(W + (size_t)(bn + row + srow) * 512 + k0 + scol,
                    &Bs[row * 64 + lane * 8]);
        }
        __syncthreads();   // drains vmcnt before barrier
#pragma unroll
        for (int kk = 0; kk < 64; kk += 32) {
            bf16x8 af[4], bfr[4];
#pragma unroll
            for (int i = 0; i < 4; i++) {
                af[i]  = *(const bf16x8*)(&As[(wm + i * 16 + l16) * 64 + kk + quad * 8]);
                bfr[i] = *(const bf16x8*)(&Bs[(wn + i * 16 + l16) * 64 + kk + quad * 8]);
            }
#pragma unroll
            for (int i = 0; i < 4; i++)
#pragma unroll
                for (int j = 0; j < 4; j++)
                    acc[i][j] = __builtin_amdgcn_mfma_f32_16x16x32_bf16(
                        af[i], bfr[j], acc[i][j], 0, 0, 0);
        }
    }
    // C/D layout: col=lane&15, row=quad*4+reg
#pragma unroll
    for (int i = 0; i < 4; i++) {
        int row = bm + wm + i * 16 + quad * 4;
#pragma unroll
        for (int j = 0; j < 4; j++) {
            int col = bn + wn + j * 16 + l16;
            float bv = bias[col];
#pragma unroll
            for (int r = 0; r < 4; r++)
                C[(size_t)(row + r) * 512 + col] = f2bf(acc[i][j][r] + bv);
        }
    }
}

// ---------------- top-k gather attention, one block per (n,b)
__global__ __launch_bounds__(256)
void attn_kernel(const u16* __restrict__ Qh, const u16* __restrict__ Kh,
                 const u16* __restrict__ Vh, const int* __restrict__ rns,
                 float* __restrict__ out) {
    __shared__ float sq[NH * 72];     // q row fp32, padded head stride
    __shared__ int   sidx[TOPK];
    __shared__ int   srow[TOPK];
    __shared__ float sval[TOPK];
    __shared__ float ss[TOPK][9];     // [slot][head], padded
    __shared__ float sw[TOPK][9];

    const int bid = blockIdx.x;
    const int n = bid >> 2;
    const int b = bid & 3;
    const int tid = threadIdx.x;
    const int lane = tid & 63;

    if (tid < TOPK) {
        int mi = rns[((b * NP + n) * TOPK) + tid];
        sidx[tid] = mi;
        srow[tid] = (mi * BS + b) * DIM;
    }
    {   // q row -> LDS fp32
        const u16* qrow = Qh + (size_t)(n * BS + b) * DIM;
        unsigned int u = *(const unsigned int*)(qrow + tid * 2);
        int e0 = tid * 2;
        sq[(e0 >> 6) * 72 + (e0 & 63)]       = bf2f((u16)(u & 0xffff));
        sq[(e0 >> 6) * 72 + ((e0 + 1) & 63)] = bf2f((u16)(u >> 16));
    }
    __syncthreads();
    if (tid < TOPK) {   // dedupe: keep first occurrence (matches ref's set-mask)
        float v = 1.0f;
        int me = sidx[tid];
        for (int j = 0; j < tid; j++)
            if (sidx[j] == me) v = 0.0f;
        sval[tid] = v;
    }
    __syncthreads();
    {   // scores: thread -> (slot i, head h)
        const int i = tid >> 3;
        const int h = tid & 7;
        const u16* krow = Kh + srow[i] + h * DH;
        const float* qh = sq + h * 72;
        float acc = 0.f;
#pragma unroll
        for (int d = 0; d < DH; d += 8) {
            uint4 kv = *(const uint4*)(krow + d);
            float4 qa = *(const float4*)(qh + d);
            float4 qb = *(const float4*)(qh + d + 4);
            acc += qa.x * bf2f((u16)(kv.x & 0xffff)) + qa.y * bf2f((u16)(kv.x >> 16))
                 + qa.z * bf2f((u16)(kv.y & 0xffff)) + qa.w * bf2f((u16)(kv.y >> 16))
                 + qb.x * bf2f((u16)(kv.z & 0xffff)) + qb.y * bf2f((u16)(kv.z >> 16))
                 + qb.z * bf2f((u16)(kv.w & 0xffff)) + qb.w * bf2f((u16)(kv.w >> 16));
        }
        ss[i][h] = (sval[i] > 0.f) ? acc * 0.125f : -1e30f;
    }
    __syncthreads();
    {   // parallel softmax: 32 slots per head in one half-wave
        const int h = tid >> 5;
        const int i = tid & 31;
        float val = ss[i][h];
        float m = val;
#pragma unroll
        for (int msk = 1; msk < 32; msk <<= 1) m = fmaxf(m, __shfl_xor(m, msk, 64));
        float e = __expf(val - m);
        float s = e;
#pragma unroll
        for (int msk = 1; msk < 32; msk <<= 1) s += __shfl_xor(s, msk, 64);
        sw[i][h] = e / s;
    }
    __syncthreads();
    {   // out: thread = (e-group of 8, slot-quarter); quad-shuffle reduce
        const int wv   = tid >> 6;
        const int part = lane & 3;
        const int e8   = (wv * 16 + (lane >> 2)) * 8;
        const int h    = e8 >> 6;
        float a[8] = {0, 0, 0, 0, 0, 0, 0, 0};
#pragma unroll
        for (int j = 0; j < 8; j++) {
            int i = part * 8 + j;
            float w = sw[i][h];
            uint4 vv = *(const uint4*)(Vh + srow[i] + e8);
            a[0] += w * bf2f((u16)(vv.x & 0xffff)); a[1] += w * bf2f((u16)(vv.x >> 16));
            a[2] += w * bf2f((u16)(vv.y & 0xffff)); a[3] += w * bf2f((u16)(vv.y >> 16));
            a[4] += w * bf2f((u16)(vv.z & 0xffff)); a[5] += w * bf2f((u16)(vv.z >> 16));
            a[6] += w * bf2f((u16)(vv.w & 0xffff)); a[7] += w * bf2f((u16)(vv.w >> 16));
        }
#pragma unroll
        for (int j = 0; j < 8; j++) {
            a[j] += __shfl_xor(a[j], 1, 64);
            a[j] += __shfl_xor(a[j], 2, 64);
        }
        if (part == 0) {
            float* op = out + (size_t)(n * BS + b) * DIM + e8;
            float4 o0 = {a[0], a[1], a[2], a[3]};
            float4 o1 = {a[4], a[5], a[6], a[7]};
            *(float4*)op = o0;
            *((float4*)op + 1) = o1;
        }
    }
}

extern "C" void kernel_launch(void* const* d_in, const int* in_sizes, int n_in,
                              void* d_out, int out_size, void* d_ws, size_t ws_size,
                              hipStream_t stream) {
    const float* q  = (const float*)d_in[0];
    const float* k  = (const float*)d_in[1];
    const float* v  = (const float*)d_in[2];
    const int* rns  = (const int*)d_in[3];
    const float* W1 = (const float*)d_in[4];
    const float* b1 = (const float*)d_in[5];
    const float* W2 = (const float*)d_in[6];
    const float* b2 = (const float*)d_in[7];
    const float* W3 = (const float*)d_in[8];
    const float* b3 = (const float*)d_in[9];
    float* out = (float*)d_out;

    u16* ws   = (u16*)d_ws;
    u16* wall = ws;                        // 3 * 512*512 bf16 weights
    u16* act  = wall + 786432;             // q(2097152) | k(8388608) | v(8388608)
    u16* proj = act + 18874368;            // Qh | Kh | Vh, same offsets
    u16* Qh = proj;
    u16* Kh = proj + 2097152;
    u16* Vh = proj + 10485760;
    // total ws use: 77 MB

    cvt_all<<<19200, 256, 0, stream>>>(W1, W2, W3, q, k, v, wall, act);
    proj_gemm<<<dim3(4, 128, 3), 256, 0, stream>>>(act, wall, b1, b2, b3, proj);
    attn_kernel<<<NP * BS, 256, 0, stream>>>(Qh, Kh, Vh, rns, out);
}

// Round 3
// 189.221 us; speedup vs baseline: 1.0797x; 1.0499x over previous
//
#include <hip/hip_runtime.h>
#include <stdint.h>

#define NH   8
#define DIM  512
#define NP   1024
#define MNP  4096
#define BS   4
#define TOPK 32
#define DH   64

typedef unsigned short u16;
typedef __attribute__((ext_vector_type(8))) short bf16x8;
typedef __attribute__((ext_vector_type(4))) float f32x4;

__device__ __forceinline__ u16 f2bf(float f) {
    union { float f; unsigned u; } x; x.f = f;
    unsigned r = x.u + 0x7FFFu + ((x.u >> 16) & 1u);   // RNE
    return (u16)(r >> 16);
}
__device__ __forceinline__ float bf2f(u16 h) {
    union { unsigned u; float f; } x; x.u = ((unsigned)h) << 16;
    return x.f;
}

// async 16B global -> LDS (global_load_lds_dwordx4). LDS dest must be
// wave-uniform base + lane*16 (contiguous in lane order, no padding).
__device__ __forceinline__ void async16(const void* g, void* l) {
    __builtin_amdgcn_global_load_lds(
        (const __attribute__((address_space(1))) unsigned int*)g,
        (__attribute__((address_space(3))) unsigned int*)l, 16, 0, 0);
}

// ---------------- single fp32 -> bf16 pass: W1|W2|W3 -> wall, q|k|v -> act
__global__ void cvt_all(const float* __restrict__ W1, const float* __restrict__ W2,
                        const float* __restrict__ W3, const float* __restrict__ q,
                        const float* __restrict__ k,  const float* __restrict__ v,
                        u16* __restrict__ wall, u16* __restrict__ act) {
    size_t i = ((size_t)blockIdx.x * 256 + threadIdx.x) * 4;
    const float* s; u16* d;
    if (i < 786432) {
        d = wall + i;
        s = (i < 262144) ? W1 + i : (i < 524288) ? W2 + (i - 262144) : W3 + (i - 524288);
    } else {
        size_t j = i - 786432;
        d = act + j;
        s = (j < 2097152) ? q + j : (j < 10485760) ? k + (j - 2097152) : v + (j - 10485760);
    }
    float4 val = *(const float4*)s;
    ushort4 o;
    o.x = f2bf(val.x); o.y = f2bf(val.y); o.z = f2bf(val.z); o.w = f2bf(val.w);
    *(ushort4*)d = o;
}

// ---------------- fused projection GEMM (z selects q/k/v), m97-style
__global__ __launch_bounds__(256, 2)
void proj_gemm(const u16* __restrict__ act, const u16* __restrict__ wall,
               const float* __restrict__ b1, const float* __restrict__ b2,
               const float* __restrict__ b3, u16* __restrict__ outall) {
    __shared__ u16 As[128 * 64];
    __shared__ u16 Bs[128 * 64];

    const int z = blockIdx.z;
    if (z == 0 && blockIdx.y >= 32) return;   // q has M=4096 (32 y-tiles)
    const size_t aoff = (z == 0) ? 0u : (z == 1) ? 2097152u : 10485760u;
    const u16* A = act + aoff;
    const u16* W = wall + (size_t)z * 262144;
    const float* bias = (z == 0) ? b1 : (z == 1) ? b2 : b3;
    u16* C = outall + aoff;

    const int tid  = threadIdx.x;
    const int bm   = blockIdx.y * 128;
    const int bn   = blockIdx.x * 128;
    const int wave = tid >> 6;
    const int lane = tid & 63;
    const int wm   = (wave & 1) * 64;
    const int wn   = (wave >> 1) * 64;
    const int l16  = lane & 15;
    const int quad = lane >> 4;

    const int srow = lane >> 3;        // 0..7
    const int scol = (lane & 7) * 8;   // 0..56 (bf16 elems, 16B granules)

    f32x4 acc[4][4] = {};

    for (int k0 = 0; k0 < 512; k0 += 64) {
        __syncthreads();
#pragma unroll
        for (int r = 0; r < 4; r++) {
            int row = wave * 32 + r * 8;        // wave-uniform LDS base row
            async16(A + (size_t)(bm + row + srow) * 512 + k0 + scol,
                    &As[row * 64 + lane * 8]);
            async16(W + (size_t)(bn + row + srow) * 512 + k0 + scol,
                    &Bs[row * 64 + lane * 8]);
        }
        __syncthreads();   // drains vmcnt before barrier
#pragma unroll
        for (int kk = 0; kk < 64; kk += 32) {
            bf16x8 af[4], bfr[4];
#pragma unroll
            for (int i = 0; i < 4; i++) {
                af[i]  = *(const bf16x8*)(&As[(wm + i * 16 + l16) * 64 + kk + quad * 8]);
                bfr[i] = *(const bf16x8*)(&Bs[(wn + i * 16 + l16) * 64 + kk + quad * 8]);
            }
#pragma unroll
            for (int i = 0; i < 4; i++)
#pragma unroll
                for (int j = 0; j < 4; j++)
                    acc[i][j] = __builtin_amdgcn_mfma_f32_16x16x32_bf16(
                        af[i], bfr[j], acc[i][j], 0, 0, 0);
        }
    }
    // C/D layout: col=lane&15, row=quad*4+reg
#pragma unroll
    for (int i = 0; i < 4; i++) {
        int row = bm + wm + i * 16 + quad * 4;
#pragma unroll
        for (int j = 0; j < 4; j++) {
            int col = bn + wn + j * 16 + l16;
            float bv = bias[col];
#pragma unroll
            for (int r = 0; r < 4; r++)
                C[(size_t)(row + r) * 512 + col] = f2bf(acc[i][j][r] + bv);
        }
    }
}

// ---------------- barrier-free top-k gather attention: one WAVE per (n,b)
// lane mapping, score phase:  slot = lane>>1, dim-half = lane&1
// lane mapping, V phase:      head = lane>>3, elems [lane*8, lane*8+8)
__global__ __launch_bounds__(256)
void attn_kernel(const u16* __restrict__ Qh, const u16* __restrict__ Kh,
                 const u16* __restrict__ Vh, const int* __restrict__ rns,
                 float* __restrict__ out) {
    __shared__ float sq[4][512];        // q row fp32, wave-private
    __shared__ float swt[4][32 * 9];    // weights [slot][head], stride-9 pad
    __shared__ int   srw[4][TOPK];      // gathered row offsets

    const int wv   = threadIdx.x >> 6;
    const int lane = threadIdx.x & 63;
    const int pair = blockIdx.x * 4 + wv;   // (n,b) id
    const int n = pair >> 2;
    const int b = pair & 3;
    const int s   = lane >> 1;   // slot
    const int sub = lane & 1;    // dim half

    // slot index + row (both lanes of pair load same addr -> same value)
    int myidx = rns[(b * NP + n) * TOPK + s];
    int myrow = (myidx * BS + b) * DIM;
    if (sub == 0) srw[wv][s] = myrow;

    // dedupe: dup iff an earlier slot has the same index (matches ref set-mask)
    bool dup = false;
#pragma unroll
    for (int j = 0; j < TOPK; j++) {
        int other = __shfl(myidx, j * 2, 64);
        dup = dup || ((j < s) && (other == myidx));
    }

    // q row -> LDS fp32 (16B bf16 load per lane)
    {
        const u16* qrow = Qh + (size_t)pair * DIM;
        uint4 qv = *(const uint4*)(qrow + lane * 8);
        float4 f0 = { bf2f((u16)qv.x), bf2f((u16)(qv.x >> 16)),
                      bf2f((u16)qv.y), bf2f((u16)(qv.y >> 16)) };
        float4 f1 = { bf2f((u16)qv.z), bf2f((u16)(qv.z >> 16)),
                      bf2f((u16)qv.w), bf2f((u16)(qv.w >> 16)) };
        *(float4*)(&sq[wv][lane * 8])     = f0;
        *(float4*)(&sq[wv][lane * 8 + 4]) = f1;
    }
    __builtin_amdgcn_wave_barrier();   // wave-private LDS: scheduling pin only

    // scores: each lane computes 8 half-dots (its slot, its 32-dim half, 8 heads)
    const float* qw = sq[wv];
    float sc[NH];
#pragma unroll
    for (int h = 0; h < NH; h++) {
        const u16* kp = Kh + myrow + h * DH + sub * 32;
        const float* qp = qw + h * DH + sub * 32;
        float acc = 0.f;
#pragma unroll
        for (int d = 0; d < 32; d += 8) {
            uint4 kv = *(const uint4*)(kp + d);
            acc += qp[d + 0] * bf2f((u16)kv.x) + qp[d + 1] * bf2f((u16)(kv.x >> 16))
                 + qp[d + 2] * bf2f((u16)kv.y) + qp[d + 3] * bf2f((u16)(kv.y >> 16))
                 + qp[d + 4] * bf2f((u16)kv.z) + qp[d + 5] * bf2f((u16)(kv.z >> 16))
                 + qp[d + 6] * bf2f((u16)kv.w) + qp[d + 7] * bf2f((u16)(kv.w >> 16));
        }
        sc[h] = acc;
    }
    // combine dim-halves; mask dups (exp(-1e30-m) -> 0, matches ref softmax)
#pragma unroll
    for (int h = 0; h < NH; h++) {
        sc[h] += __shfl_xor(sc[h], 1, 64);
        sc[h] = dup ? -1e30f : sc[h] * 0.125f;
    }
    // softmax over 32 slots via stride-{2..32} butterflies (both sub-lanes run it)
    float w[NH];
#pragma unroll
    for (int h = 0; h < NH; h++) {
        float m = sc[h];
        m = fmaxf(m, __shfl_xor(m, 2, 64));
        m = fmaxf(m, __shfl_xor(m, 4, 64));
        m = fmaxf(m, __shfl_xor(m, 8, 64));
        m = fmaxf(m, __shfl_xor(m, 16, 64));
        m = fmaxf(m, __shfl_xor(m, 32, 64));
        float e = __expf(sc[h] - m);
        float t = e;
        t += __shfl_xor(t, 2, 64);
        t += __shfl_xor(t, 4, 64);
        t += __shfl_xor(t, 8, 64);
        t += __shfl_xor(t, 16, 64);
        t += __shfl_xor(t, 32, 64);
        w[h] = e / t;
    }
    if (sub == 0) {   // stride-9 layout: writes stride 36B -> conflict-free
#pragma unroll
        for (int h = 0; h < NH; h++) swt[wv][s * 9 + h] = w[h];
    }
    __builtin_amdgcn_wave_barrier();

    // V phase: lane covers 8 output elems (16B V load) x 32 slots
    const int h  = lane >> 3;
    const int e8 = lane * 8;
    float a[8] = {0, 0, 0, 0, 0, 0, 0, 0};
#pragma unroll 8
    for (int si = 0; si < TOPK; si++) {
        int   row = srw[wv][si];              // broadcast read
        float wgt = swt[wv][si * 9 + h];      // 8 consecutive addrs: no conflict
        uint4 vv = *(const uint4*)(Vh + row + e8);
        a[0] += wgt * bf2f((u16)vv.x); a[1] += wgt * bf2f((u16)(vv.x >> 16));
        a[2] += wgt * bf2f((u16)vv.y); a[3] += wgt * bf2f((u16)(vv.y >> 16));
        a[4] += wgt * bf2f((u16)vv.z); a[5] += wgt * bf2f((u16)(vv.z >> 16));
        a[6] += wgt * bf2f((u16)vv.w); a[7] += wgt * bf2f((u16)(vv.w >> 16));
    }
    float* op = out + (size_t)pair * DIM + e8;
    float4 o0 = {a[0], a[1], a[2], a[3]};
    float4 o1 = {a[4], a[5], a[6], a[7]};
    *(float4*)op       = o0;
    *((float4*)op + 1) = o1;
}

extern "C" void kernel_launch(void* const* d_in, const int* in_sizes, int n_in,
                              void* d_out, int out_size, void* d_ws, size_t ws_size,
                              hipStream_t stream) {
    const float* q  = (const float*)d_in[0];
    const float* k  = (const float*)d_in[1];
    const float* v  = (const float*)d_in[2];
    const int* rns  = (const int*)d_in[3];
    const float* W1 = (const float*)d_in[4];
    const float* b1 = (const float*)d_in[5];
    const float* W2 = (const float*)d_in[6];
    const float* b2 = (const float*)d_in[7];
    const float* W3 = (const float*)d_in[8];
    const float* b3 = (const float*)d_in[9];
    float* out = (float*)d_out;

    u16* ws   = (u16*)d_ws;
    u16* wall = ws;                        // 3 * 512*512 bf16 weights
    u16* act  = wall + 786432;             // q(2097152) | k(8388608) | v(8388608)
    u16* proj = act + 18874368;            // Qh | Kh | Vh, same offsets
    u16* Qh = proj;
    u16* Kh = proj + 2097152;
    u16* Vh = proj + 10485760;

    cvt_all<<<19200, 256, 0, stream>>>(W1, W2, W3, q, k, v, wall, act);
    proj_gemm<<<dim3(4, 128, 3), 256, 0, stream>>>(act, wall, b1, b2, b3, proj);
    attn_kernel<<<NP * BS / 4, 256, 0, stream>>>(Qh, Kh, Vh, rns, out);
}

// Round 4
// 187.725 us; speedup vs baseline: 1.0884x; 1.0080x over previous
//
#include <hip/hip_runtime.h>
#include <stdint.h>

#define NH   8
#define DIM  512
#define NP   1024
#define MNP  4096
#define BS   4
#define TOPK 32
#define DH   64

typedef unsigned short u16;
typedef __attribute__((ext_vector_type(8))) short bf16x8;
typedef __attribute__((ext_vector_type(4))) float f32x4;

__device__ __forceinline__ u16 f2bf(float f) {
    union { float f; unsigned u; } x; x.f = f;
    unsigned r = x.u + 0x7FFFu + ((x.u >> 16) & 1u);   // RNE
    return (u16)(r >> 16);
}
__device__ __forceinline__ float bf2f(u16 h) {
    union { unsigned u; float f; } x; x.u = ((unsigned)h) << 16;
    return x.f;
}

// async 16B global -> LDS (global_load_lds_dwordx4). LDS dest is wave-uniform
// base + lane*16: lane-contiguous, no padding possible.
__device__ __forceinline__ void async16(const void* g, void* l) {
    __builtin_amdgcn_global_load_lds(
        (const __attribute__((address_space(1))) unsigned int*)g,
        (__attribute__((address_space(3))) unsigned int*)l, 16, 0, 0);
}

// ---------------- single fp32 -> bf16 pass: W1|W2|W3 -> wall, q|k|v -> act
__global__ void cvt_all(const float* __restrict__ W1, const float* __restrict__ W2,
                        const float* __restrict__ W3, const float* __restrict__ q,
                        const float* __restrict__ k,  const float* __restrict__ v,
                        u16* __restrict__ wall, u16* __restrict__ act) {
    size_t i = ((size_t)blockIdx.x * 256 + threadIdx.x) * 4;
    const float* s; u16* d;
    if (i < 786432) {
        d = wall + i;
        s = (i < 262144) ? W1 + i : (i < 524288) ? W2 + (i - 262144) : W3 + (i - 524288);
    } else {
        size_t j = i - 786432;
        d = act + j;
        s = (j < 2097152) ? q + j : (j < 10485760) ? k + (j - 2097152) : v + (j - 10485760);
    }
    float4 val = *(const float4*)s;
    ushort4 o;
    o.x = f2bf(val.x); o.y = f2bf(val.y); o.z = f2bf(val.z); o.w = f2bf(val.w);
    *(ushort4*)d = o;
}

// ---------------- fused projection GEMM (z selects q/k/v), m97-style +
// XOR-swizzled LDS: 16B granule (r,c) lives at slot c^(r&7) within row r.
// Swizzle applied at stage time by permuting WHICH granule each lane fetches
// (same 128B segment -> coalescing unchanged); reads index g^(r&7) -> banks
// spread over all 32, 2-way alias only (free).
__global__ __launch_bounds__(256, 4)
void proj_gemm(const u16* __restrict__ act, const u16* __restrict__ wall,
               const float* __restrict__ b1, const float* __restrict__ b2,
               const float* __restrict__ b3, u16* __restrict__ outall) {
    __shared__ u16 As[128 * 64];
    __shared__ u16 Bs[128 * 64];

    const int z = blockIdx.z;
    if (z == 0 && blockIdx.y >= 32) return;   // q has M=4096 (32 y-tiles)
    const size_t aoff = (z == 0) ? 0u : (z == 1) ? 2097152u : 10485760u;
    const u16* A = act + aoff;
    const u16* W = wall + (size_t)z * 262144;
    const float* bias = (z == 0) ? b1 : (z == 1) ? b2 : b3;
    u16* C = outall + aoff;

    const int tid  = threadIdx.x;
    const int bm   = blockIdx.y * 128;
    const int bn   = blockIdx.x * 128;
    const int wave = tid >> 6;
    const int lane = tid & 63;
    const int wm   = (wave & 1) * 64;
    const int wn   = (wave >> 1) * 64;
    const int l16  = lane & 15;
    const int quad = lane >> 4;

    const int srow = lane >> 3;                    // 0..7 (== row&7: bases are mult of 8)
    const int scol = ((lane & 7) ^ srow) * 8;      // swizzle-permuted granule fetch

    f32x4 acc[4][4] = {};

    for (int k0 = 0; k0 < 512; k0 += 64) {
        __syncthreads();
#pragma unroll
        for (int r = 0; r < 4; r++) {
            int row = wave * 32 + r * 8;           // wave-uniform LDS base row
            async16(A + (size_t)(bm + row + srow) * 512 + k0 + scol,
                    &As[row * 64 + lane * 8]);
            async16(W + (size_t)(bn + row + srow) * 512 + k0 + scol,
                    &Bs[row * 64 + lane * 8]);
        }
        __syncthreads();   // drains vmcnt before barrier
#pragma unroll
        for (int kk = 0; kk < 64; kk += 32) {
            bf16x8 af[4], bfr[4];
            const int g = (kk >> 3) + quad;        // logical granule index
#pragma unroll
            for (int i = 0; i < 4; i++) {
                int ra = wm + i * 16 + l16;
                int rb = wn + i * 16 + l16;
                af[i]  = *(const bf16x8*)(&As[ra * 64 + ((g ^ (ra & 7)) << 3)]);
                bfr[i] = *(const bf16x8*)(&Bs[rb * 64 + ((g ^ (rb & 7)) << 3)]);
            }
#pragma unroll
            for (int i = 0; i < 4; i++)
#pragma unroll
                for (int j = 0; j < 4; j++)
                    acc[i][j] = __builtin_amdgcn_mfma_f32_16x16x32_bf16(
                        af[i], bfr[j], acc[i][j], 0, 0, 0);
        }
    }
    // C/D layout: col=lane&15, row=quad*4+reg
#pragma unroll
    for (int i = 0; i < 4; i++) {
        int row = bm + wm + i * 16 + quad * 4;
#pragma unroll
        for (int j = 0; j < 4; j++) {
            int col = bn + wn + j * 16 + l16;
            float bv = bias[col];
#pragma unroll
            for (int r = 0; r < 4; r++)
                C[(size_t)(row + r) * 512 + col] = f2bf(acc[i][j][r] + bv);
        }
    }
}

// ---------------- barrier-free top-k gather attention: one WAVE per (n,b)
__global__ __launch_bounds__(256)
void attn_kernel(const u16* __restrict__ Qh, const u16* __restrict__ Kh,
                 const u16* __restrict__ Vh, const int* __restrict__ rns,
                 float* __restrict__ out) {
    __shared__ float sq[4][512];        // q row fp32, wave-private
    __shared__ float swt[4][32 * 9];    // weights [slot][head], stride-9 pad
    __shared__ int   srw[4][TOPK];      // gathered row offsets

    const int wv   = threadIdx.x >> 6;
    const int lane = threadIdx.x & 63;
    const int pair = blockIdx.x * 4 + wv;   // (n,b) id
    const int n = pair >> 2;
    const int b = pair & 3;
    const int s   = lane >> 1;   // slot
    const int sub = lane & 1;    // dim half

    int myidx = rns[(b * NP + n) * TOPK + s];
    int myrow = (myidx * BS + b) * DIM;
    if (sub == 0) srw[wv][s] = myrow;

    // dedupe: dup iff an earlier slot has the same index (matches ref set-mask)
    bool dup = false;
#pragma unroll
    for (int j = 0; j < TOPK; j++) {
        int other = __shfl(myidx, j * 2, 64);
        dup = dup || ((j < s) && (other == myidx));
    }

    // q row -> LDS fp32 (16B bf16 load per lane)
    {
        const u16* qrow = Qh + (size_t)pair * DIM;
        uint4 qv = *(const uint4*)(qrow + lane * 8);
        float4 f0 = { bf2f((u16)qv.x), bf2f((u16)(qv.x >> 16)),
                      bf2f((u16)qv.y), bf2f((u16)(qv.y >> 16)) };
        float4 f1 = { bf2f((u16)qv.z), bf2f((u16)(qv.z >> 16)),
                      bf2f((u16)qv.w), bf2f((u16)(qv.w >> 16)) };
        *(float4*)(&sq[wv][lane * 8])     = f0;
        *(float4*)(&sq[wv][lane * 8 + 4]) = f1;
    }
    __builtin_amdgcn_wave_barrier();   // wave-private LDS: scheduling pin only

    // scores: each lane computes 8 half-dots (its slot, its 32-dim half)
    const float* qw = sq[wv];
    float sc[NH];
#pragma unroll
    for (int h = 0; h < NH; h++) {
        const u16* kp = Kh + myrow + h * DH + sub * 32;
        const float* qp = qw + h * DH + sub * 32;
        float acc = 0.f;
#pragma unroll
        for (int d = 0; d < 32; d += 8) {
            uint4 kv = *(const uint4*)(kp + d);
            acc += qp[d + 0] * bf2f((u16)kv.x) + qp[d + 1] * bf2f((u16)(kv.x >> 16))
                 + qp[d + 2] * bf2f((u16)kv.y) + qp[d + 3] * bf2f((u16)(kv.y >> 16))
                 + qp[d + 4] * bf2f((u16)kv.z) + qp[d + 5] * bf2f((u16)(kv.z >> 16))
                 + qp[d + 6] * bf2f((u16)kv.w) + qp[d + 7] * bf2f((u16)(kv.w >> 16));
        }
        sc[h] = acc;
    }
#pragma unroll
    for (int h = 0; h < NH; h++) {
        sc[h] += __shfl_xor(sc[h], 1, 64);
        sc[h] = dup ? -1e30f : sc[h] * 0.125f;
    }
    // softmax over 32 slots via stride-{2..32} butterflies
    float w[NH];
#pragma unroll
    for (int h = 0; h < NH; h++) {
        float m = sc[h];
        m = fmaxf(m, __shfl_xor(m, 2, 64));
        m = fmaxf(m, __shfl_xor(m, 4, 64));
        m = fmaxf(m, __shfl_xor(m, 8, 64));
        m = fmaxf(m, __shfl_xor(m, 16, 64));
        m = fmaxf(m, __shfl_xor(m, 32, 64));
        float e = __expf(sc[h] - m);
        float t = e;
        t += __shfl_xor(t, 2, 64);
        t += __shfl_xor(t, 4, 64);
        t += __shfl_xor(t, 8, 64);
        t += __shfl_xor(t, 16, 64);
        t += __shfl_xor(t, 32, 64);
        w[h] = e / t;
    }
    if (sub == 0) {
#pragma unroll
        for (int h = 0; h < NH; h++) swt[wv][s * 9 + h] = w[h];
    }
    __builtin_amdgcn_wave_barrier();

    // V phase: lane covers 8 output elems (16B V load) x 32 slots
    const int h  = lane >> 3;
    const int e8 = lane * 8;
    float a[8] = {0, 0, 0, 0, 0, 0, 0, 0};
#pragma unroll 8
    for (int si = 0; si < TOPK; si++) {
        int   row = srw[wv][si];              // broadcast read
        float wgt = swt[wv][si * 9 + h];      // 8 consecutive addrs: no conflict
        uint4 vv = *(const uint4*)(Vh + row + e8);
        a[0] += wgt * bf2f((u16)vv.x); a[1] += wgt * bf2f((u16)(vv.x >> 16));
        a[2] += wgt * bf2f((u16)vv.y); a[3] += wgt * bf2f((u16)(vv.y >> 16));
        a[4] += wgt * bf2f((u16)vv.z); a[5] += wgt * bf2f((u16)(vv.z >> 16));
        a[6] += wgt * bf2f((u16)vv.w); a[7] += wgt * bf2f((u16)(vv.w >> 16));
    }
    float* op = out + (size_t)pair * DIM + e8;
    float4 o0 = {a[0], a[1], a[2], a[3]};
    float4 o1 = {a[4], a[5], a[6], a[7]};
    *(float4*)op       = o0;
    *((float4*)op + 1) = o1;
}

extern "C" void kernel_launch(void* const* d_in, const int* in_sizes, int n_in,
                              void* d_out, int out_size, void* d_ws, size_t ws_size,
                              hipStream_t stream) {
    const float* q  = (const float*)d_in[0];
    const float* k  = (const float*)d_in[1];
    const float* v  = (const float*)d_in[2];
    const int* rns  = (const int*)d_in[3];
    const float* W1 = (const float*)d_in[4];
    const float* b1 = (const float*)d_in[5];
    const float* W2 = (const float*)d_in[6];
    const float* b2 = (const float*)d_in[7];
    const float* W3 = (const float*)d_in[8];
    const float* b3 = (const float*)d_in[9];
    float* out = (float*)d_out;

    u16* ws   = (u16*)d_ws;
    u16* wall = ws;                        // 3 * 512*512 bf16 weights
    u16* act  = wall + 786432;             // q(2097152) | k(8388608) | v(8388608)
    u16* proj = act + 18874368;            // Qh | Kh | Vh, same offsets
    u16* Qh = proj;
    u16* Kh = proj + 2097152;
    u16* Vh = proj + 10485760;

    cvt_all<<<19200, 256, 0, stream>>>(W1, W2, W3, q, k, v, wall, act);
    proj_gemm<<<dim3(4, 128, 3), 256, 0, stream>>>(act, wall, b1, b2, b3, proj);
    attn_kernel<<<NP * BS / 4, 256, 0, stream>>>(Qh, Kh, Vh, rns, out);
}